// Round 14
// baseline (71.823 us; speedup 1.0000x reference)
//
#include <hip/hip_runtime.h>
#include <hip/hip_fp16.h>
#include <math.h>

// Siddon forward projection, 128^3 grid over [-1,1]^3, voxel = 1/64.
// K=8 lanes per LOR (alpha chunks), cheap packed-index serial step with
// depth-4 batch-4 load pipeline; fp16 image in workspace (L2-resident).
// Rays bucket-sorted by crossing count (16 bins, longest first, miss rays
// last); deterministic atomic-free scatter. convert+keys fused in one kernel.

static constexpr float VOX = 0.015625f;   // 2/128, exact power of two
static constexpr float INV_VOX = 64.0f;
static constexpr int   K = 8;
static constexpr int   LOGK = 3;
static constexpr int   NVOX = 128 * 128 * 128;
static constexpr int   IDX_MASK = 0x3FFFFE;   // even byte offset, < 4 MB
static constexpr int   NBINS = 16;            // bin 0 = miss, 1.. by V>>5
static constexpr int   CONV_BLOCKS = 1024;

struct TState {
  float alx, aly, alz;   // next-crossing alpha per axis
  float dax, day, daz;   // alpha increment per crossing
  float acur, aend;
  int   idx;             // packed byte offset: ix*2^15 + iy*2^8 + iz*2
  int   dix, diy, diz;   // packed per-crossing deltas (signed)
};

__device__ __forceinline__ void step4(const __half* __restrict__ image,
                                      TState& S, float dif4[4], float v4[4]) {
#pragma unroll
  for (int j = 0; j < 4; ++j) {
    float anext = fminf(fminf(S.alx, S.aly), S.alz);
    float astop = fminf(anext, S.aend);
    float dif   = fmaxf(astop - S.acur, 0.0f);
    dif4[j] = dif;
    // dead/padded steps (dif==0) read line 0 (broadcast), not random lines
    int addr = (dif > 0.0f) ? (S.idx & IDX_MASK) : 0;
    v4[j] = __half2float(*(const __half*)((const char*)image + addr));
    S.acur = astop;
    bool cx = S.alx <= anext;
    bool cy = S.aly <= anext;
    bool cz = S.alz <= anext;
    S.idx += (cx ? S.dix : 0) + (cy ? S.diy : 0) + (cz ? S.diz : 0);
    S.alx += cx ? S.dax : 0.0f;
    S.aly += cy ? S.day : 0.0f;
    S.alz += cz ? S.daz : 0.0f;
  }
}

// First plane index strictly past astart in walk order, its alpha, the alpha
// increment, the voxel containing astart, and crossing count in (astart,aend].
__device__ __forceinline__ void axis_init(float astart, float aend, float p0,
                                          float ds, float inv,
                                          int& st, int& iv, float& al, float& da,
                                          int& cnt) {
  float ts = (fmaf(astart, ds, p0) + 1.0f) * INV_VOX;
  float te = (fmaf(aend,   ds, p0) + 1.0f) * INV_VOX;
  int ip;
  if (ds > 0.0f) {
    ip = (int)floorf(ts) + 1;
    int il = (int)floorf(te); if (il > 128) il = 128;
    cnt = il - ip + 1; st = 1; iv = ip - 1;
  } else {
    ip = (int)ceilf(ts) - 1;
    int il = (int)ceilf(te); if (il < 0) il = 0;
    cnt = ip - il + 1; st = -1; iv = ip;
  }
  if (cnt < 0) cnt = 0;
  al = (fmaf((float)ip, VOX, -1.0f) - p0) * inv;
  da = VOX * fabsf(inv);
}

__device__ __forceinline__ void ray_setup(const float* L,
    float& p0x, float& p0y, float& p0z,
    float& dx, float& dy, float& dz,
    float& dsx, float& dsy, float& dsz,
    float& invx, float& invy, float& invz,
    float& amin, float& amax) {
  p0x = L[0]; p0y = L[1]; p0z = L[2];
  dx = L[3] - p0x; dy = L[4] - p0y; dz = L[5] - p0z;
  const float eps = 1e-9f;
  dsx = (fabsf(dx) < eps) ? eps : dx;
  dsy = (fabsf(dy) < eps) ? eps : dy;
  dsz = (fabsf(dz) < eps) ? eps : dz;
  invx = __builtin_amdgcn_rcpf(dsx);
  invy = __builtin_amdgcn_rcpf(dsy);
  invz = __builtin_amdgcn_rcpf(dsz);
  float a0 = (-1.0f - p0x) * invx, a1 = (1.0f - p0x) * invx;
  float axmin = fminf(a0, a1), axmax = fmaxf(a0, a1);
  a0 = (-1.0f - p0y) * invy; a1 = (1.0f - p0y) * invy;
  float aymin = fminf(a0, a1), aymax = fmaxf(a0, a1);
  a0 = (-1.0f - p0z) * invz; a1 = (1.0f - p0z) * invz;
  float azmin = fminf(a0, a1), azmax = fmaxf(a0, a1);
  amin = fmaxf(fmaxf(axmin, aymin), fmaxf(azmin, 0.0f));
  amax = fminf(fminf(axmax, aymax), fminf(azmax, 1.0f));
}

// --- fused: blocks [0,nblk) compute keys+per-block histogram;
//            blocks [nblk, nblk+CONV_BLOCKS) convert image fp32->fp16 --------
__global__ __launch_bounds__(256) void fused_prep(
    const float* __restrict__ img, __half* __restrict__ h,
    const float* __restrict__ lors, int n, int nblk,
    int* __restrict__ keys, int* __restrict__ bhist)
{
  if ((int)blockIdx.x >= nblk) {
    int i = (blockIdx.x - nblk) * blockDim.x + threadIdx.x;
    int stride = CONV_BLOCKS * blockDim.x;
    for (; i < NVOX; i += stride) h[i] = __float2half(img[i]);
    return;
  }

  __shared__ int lhist[NBINS];
  if (threadIdx.x < NBINS) lhist[threadIdx.x] = 0;
  __syncthreads();

  int i = blockIdx.x * blockDim.x + threadIdx.x;
  int bin = -1;
  if (i < n) {
    float p0x,p0y,p0z,dx,dy,dz,dsx,dsy,dsz,invx,invy,invz,amin,amax;
    ray_setup(lors + (long)i * 6, p0x,p0y,p0z, dx,dy,dz,
              dsx,dsy,dsz, invx,invy,invz, amin,amax);
    bin = 0;
    if (amax > amin) {
      int st, iv, c0, c1, c2; float al, da;
      axis_init(amin, amax, p0x, dsx, invx, st, iv, al, da, c0);
      axis_init(amin, amax, p0y, dsy, invy, st, iv, al, da, c1);
      axis_init(amin, amax, p0z, dsz, invz, st, iv, al, da, c2);
      int V = c0 + c1 + c2;            // <= 387 -> V>>5 <= 12
      bin = 1 + (V >> 5);
    }
    keys[i] = bin;
  }
  int lane = threadIdx.x & 63;
#pragma unroll
  for (int b = 0; b < NBINS; ++b) {
    unsigned long long m = __ballot(bin == b);
    if (lane == 0 && m) atomicAdd(&lhist[b], (int)__popcll(m));
  }
  __syncthreads();
  if (threadIdx.x < NBINS)
    bhist[threadIdx.x * nblk + blockIdx.x] = lhist[threadIdx.x];
}

// --- sort pass 2: per-bin exclusive scan over blocks + bin bases -------------
// one block, 256 threads; wave w handles bins w, w+4, w+8, w+12.
__global__ __launch_bounds__(256) void scan_bins(
    int* __restrict__ bhist, int nblk, int* __restrict__ base)
{
  __shared__ int tot[NBINS];
  int w = threadIdx.x >> 6, lane = threadIdx.x & 63;
  for (int bin = w; bin < NBINS; bin += 4) {
    int run = 0;
    for (int c0 = 0; c0 < nblk; c0 += 64) {
      int b = c0 + lane;
      int v = (b < nblk) ? bhist[bin * nblk + b] : 0;
      int p = v;
#pragma unroll
      for (int d = 1; d < 64; d <<= 1) {
        int o = __shfl_up(p, d);
        if (lane >= d) p += o;
      }
      if (b < nblk) bhist[bin * nblk + b] = run + (p - v);
      run += __shfl(p, 63);
    }
    if (lane == 0) tot[bin] = run;
  }
  __syncthreads();
  if (threadIdx.x == 0) {
    int run = 0;
    for (int r = 0; r < NBINS; ++r) {
      int bin = (r < NBINS - 1) ? (NBINS - 1 - r) : 0;   // 15,14,...,1,0
      base[bin] = run; run += tot[bin];
    }
  }
}

// --- sort pass 3: deterministic rank-based scatter ---------------------------
__global__ __launch_bounds__(256) void scatter_perm(
    const int* __restrict__ keys, const int* __restrict__ bhist,
    const int* __restrict__ base, int* __restrict__ perm, int n, int nblk)
{
  __shared__ int wcnt[4][NBINS];
  __shared__ int woff[4][NBINS];
  int i = blockIdx.x * blockDim.x + threadIdx.x;
  int w = threadIdx.x >> 6, lane = threadIdx.x & 63;
  int bin = (i < n) ? keys[i] : -1;
  unsigned long long lt = ((unsigned long long)1 << lane) - 1ull;
  int rank = 0;
#pragma unroll
  for (int b = 0; b < NBINS; ++b) {
    unsigned long long m = __ballot(bin == b);
    if (bin == b) rank = (int)__popcll(m & lt);
    if (lane == 0) wcnt[w][b] = (int)__popcll(m);
  }
  __syncthreads();
  if (threadIdx.x < NBINS) {
    int b = threadIdx.x, r = 0;
    for (int ww = 0; ww < 4; ++ww) { woff[ww][b] = r; r += wcnt[ww][b]; }
  }
  __syncthreads();
  if (i < n) {
    int pos = base[bin] + bhist[bin * nblk + blockIdx.x] + woff[w][bin] + rank;
    perm[pos] = i;
  }
}

// --- traversal ---------------------------------------------------------------
__global__ __launch_bounds__(256) void siddon_fp(
    const __half* __restrict__ image,
    const float* __restrict__ lors,
    float* __restrict__ out,
    const int* __restrict__ perm, int n)
{
  int t    = blockIdx.x * blockDim.x + threadIdx.x;
  int slot = t >> LOGK;
  int k    = t & (K - 1);
  if (slot >= n) return;
  int ray  = perm ? perm[slot] : slot;

  float p0x,p0y,p0z,dx,dy,dz,dsx,dsy,dsz,invx,invy,invz,amin,amax;
  ray_setup(lors + (long)ray * 6, p0x,p0y,p0z, dx,dy,dz,
            dsx,dsy,dsz, invx,invy,invz, amin,amax);

  float acc0 = 0.0f, acc1 = 0.0f;
  if (amax > amin) {
    float s      = (amax - amin) * (1.0f / (float)K);
    float astart = fmaf((float)k, s, amin);
    float aend   = (k == K - 1) ? amax : fmaf((float)(k + 1), s, amin);

    TState S;
    S.acur = astart; S.aend = aend;
    int stx, sty, stz, ivx, ivy, ivz, c0, c1, c2;
    axis_init(astart, aend, p0x, dsx, invx, stx, ivx, S.alx, S.dax, c0);
    axis_init(astart, aend, p0y, dsy, invy, sty, ivy, S.aly, S.day, c1);
    axis_init(astart, aend, p0z, dsz, invz, stz, ivz, S.alz, S.daz, c2);
    // ARITHMETIC packing (not OR): exact for transient -1 excursions (r9).
    S.idx = ivx * 32768 + ivy * 256 + ivz * 2;
    S.dix = stx * 32768;  S.diy = sty * 256;  S.diz = stz * 2;

    int ns = c0 + c1 + c2 + 2;          // segments = crossings+1, +1 margin
    int nb = (ns + 3) >> 2;             // batches of 4
    if (nb < 3) nb = 3;                 // prologue needs three batches

    float difA[4], difB[4], difC[4], difD[4];
    float vA[4], vB[4], vC[4], vD[4];

#define ISSUE(X)   step4(image, S, dif##X, v##X)
#define CONSUME(X)                                                  \
    do { acc0 = fmaf(dif##X[0], v##X[0], acc0);                     \
         acc1 = fmaf(dif##X[1], v##X[1], acc1);                     \
         acc0 = fmaf(dif##X[2], v##X[2], acc0);                     \
         acc1 = fmaf(dif##X[3], v##X[3], acc1); } while (0)

    ISSUE(A);
    ISSUE(B);
    ISSUE(C);
    int produce = nb - 3;
    while (produce >= 4) {
      ISSUE(D); CONSUME(A);
      ISSUE(A); CONSUME(B);
      ISSUE(B); CONSUME(C);
      ISSUE(C); CONSUME(D);
      produce -= 4;
    }
    if (produce == 3) {
      ISSUE(D); CONSUME(A);
      ISSUE(A); CONSUME(B);
      ISSUE(B); CONSUME(C);
      CONSUME(D); CONSUME(A); CONSUME(B);
    } else if (produce == 2) {
      ISSUE(D); CONSUME(A);
      ISSUE(A); CONSUME(B);
      CONSUME(C); CONSUME(D); CONSUME(A);
    } else if (produce == 1) {
      ISSUE(D); CONSUME(A);
      CONSUME(B); CONSUME(C); CONSUME(D);
    } else {
      CONSUME(A); CONSUME(B); CONSUME(C);
    }
#undef ISSUE
#undef CONSUME

    float rlen = sqrtf(dx * dx + dy * dy + dz * dz);
    acc0 = (acc0 + acc1) * rlen;
    acc1 = 0.0f;
  }

  // reduce the K=8 chunk partials within each 8-lane group
  float acc = acc0 + acc1;
  acc += __shfl_xor(acc, 1);
  acc += __shfl_xor(acc, 2);
  acc += __shfl_xor(acc, 4);
  if (k == 0) out[ray] = acc;
}

extern "C" void kernel_launch(void* const* d_in, const int* in_sizes, int n_in,
                              void* d_out, int out_size, void* d_ws, size_t ws_size,
                              hipStream_t stream) {
  const float* image = (const float*)d_in[0];   // [128,128,128] f32
  const float* lors  = (const float*)d_in[1];   // [N,6] f32
  float* out = (float*)d_out;                   // [N] f32
  int n = out_size;
  int nblk = (n + 255) / 256;

  // ws layout: fp16 image (4 MB) | keys[n] | perm[n] | bhist[16*nblk] | base[16]
  char* p = (char*)d_ws;
  __half* h   = (__half*)p;                       p += (size_t)NVOX * 2;
  int* keys   = (int*)p;                          p += (size_t)n * 4;
  int* perm   = (int*)p;                          p += (size_t)n * 4;
  int* bhist  = (int*)p;                          p += (size_t)NBINS * nblk * 4;
  int* base   = (int*)p;                          p += NBINS * 4;
  size_t need = (size_t)(p - (char*)d_ws);

  int* permArg = nullptr;
  if (ws_size >= need) {
    hipLaunchKernelGGL(fused_prep, dim3(nblk + CONV_BLOCKS), dim3(256), 0, stream,
                       image, h, lors, n, nblk, keys, bhist);
    hipLaunchKernelGGL(scan_bins,    dim3(1),    dim3(256), 0, stream,
                       bhist, nblk, base);
    hipLaunchKernelGGL(scatter_perm, dim3(nblk), dim3(256), 0, stream,
                       keys, bhist, base, perm, n, nblk);
    permArg = perm;
  } else {
    // fallback: no sort (should not happen with provided workspace)
    hipLaunchKernelGGL(fused_prep, dim3(CONV_BLOCKS), dim3(256), 0, stream,
                       image, h, lors, 0, 0, keys, bhist);
  }

  long total = (long)n * K;
  int block = 256;
  int grid = (int)((total + block - 1) / block);
  hipLaunchKernelGGL(siddon_fp, dim3(grid), dim3(block), 0, stream,
                     h, lors, out, permArg, n);
}

// Round 16
// 54.574 us; speedup vs baseline: 1.3161x; 1.3161x over previous
//
#include <hip/hip_runtime.h>
#include <hip/hip_fp16.h>
#include <math.h>

// Siddon forward projection, 128^3 grid over [-1,1]^3, voxel = 1/64.
// Two dispatches: (1) convert fp32 image -> fp16 in 4x4x4 BRICK layout
// (brick = 128B; a 64B line covers a 2x4x4 region -> ~2-3x fewer cache-line
// touches per ray than linear z-order), (2) traversal: K=16 lanes per LOR,
// cheap incremental step keeping (ix,iy,iz), brick address computed per step,
// dead/padded steps masked to line 0 (validated r12), depth-3 load pipeline.

static constexpr float VOX = 0.015625f;   // 2/128, exact power of two
static constexpr float INV_VOX = 64.0f;
static constexpr int   K = 16;
static constexpr int   LOGK = 4;
static constexpr int   NVOX = 128 * 128 * 128;
static constexpr int   IDX_MASK = 0x3FFFFE;   // even byte offset, < 4 MB

struct TState {
  float alx, aly, alz;   // next-crossing alpha per axis
  float dax, day, daz;   // alpha increment per crossing
  float acur, aend;
  int   ix, iy, iz;      // current voxel
  int   stx, sty, stz;   // walk direction
};

// bricked halfword address: (bx<<16|by<<11|bz<<6|lx<<4|ly<<2|lz)*2 bytes
__device__ __forceinline__ int brick_addr(int ix, int iy, int iz) {
  int hx = ((ix & 0x7C) << 14) | ((ix & 3) << 4);
  int hy = ((iy & 0x7C) << 9)  | ((iy & 3) << 2);
  int hz = ((iz & 0x7C) << 4)  | (iz & 3);
  return ((hx | hy | hz) << 1) & IDX_MASK;
}

__device__ __forceinline__ void step4(const __half* __restrict__ image,
                                      TState& S, float dif4[4], float v4[4]) {
#pragma unroll
  for (int j = 0; j < 4; ++j) {
    float anext = fminf(fminf(S.alx, S.aly), S.alz);
    float astop = fminf(anext, S.aend);
    float dif   = fmaxf(astop - S.acur, 0.0f);
    dif4[j] = dif;
    // dead/padded steps (dif==0) broadcast-read line 0, not random lines
    int addr = (dif > 0.0f) ? brick_addr(S.ix, S.iy, S.iz) : 0;
    v4[j] = __half2float(*(const __half*)((const char*)image + addr));
    S.acur = astop;
    bool cx = S.alx <= anext;
    bool cy = S.aly <= anext;
    bool cz = S.alz <= anext;
    S.ix += cx ? S.stx : 0;  S.alx += cx ? S.dax : 0.0f;
    S.iy += cy ? S.sty : 0;  S.aly += cy ? S.day : 0.0f;
    S.iz += cz ? S.stz : 0;  S.alz += cz ? S.daz : 0.0f;
  }
}

// First plane index strictly past astart in walk order, its alpha, the alpha
// increment, the voxel containing astart, and crossing count in (astart,aend].
__device__ __forceinline__ void axis_init(float astart, float aend, float p0,
                                          float ds, float inv,
                                          int& st, int& iv, float& al, float& da,
                                          int& cnt) {
  float ts = (fmaf(astart, ds, p0) + 1.0f) * INV_VOX;
  float te = (fmaf(aend,   ds, p0) + 1.0f) * INV_VOX;
  int ip;
  if (ds > 0.0f) {
    ip = (int)floorf(ts) + 1;
    int il = (int)floorf(te); if (il > 128) il = 128;
    cnt = il - ip + 1; st = 1; iv = ip - 1;
  } else {
    ip = (int)ceilf(ts) - 1;
    int il = (int)ceilf(te); if (il < 0) il = 0;
    cnt = ip - il + 1; st = -1; iv = ip;
  }
  if (cnt < 0) cnt = 0;
  al = (fmaf((float)ip, VOX, -1.0f) - p0) * inv;
  da = VOX * fabsf(inv);
}

__device__ __forceinline__ void ray_setup(const float* L,
    float& p0x, float& p0y, float& p0z,
    float& dx, float& dy, float& dz,
    float& dsx, float& dsy, float& dsz,
    float& invx, float& invy, float& invz,
    float& amin, float& amax) {
  p0x = L[0]; p0y = L[1]; p0z = L[2];
  dx = L[3] - p0x; dy = L[4] - p0y; dz = L[5] - p0z;
  const float eps = 1e-9f;
  dsx = (fabsf(dx) < eps) ? eps : dx;
  dsy = (fabsf(dy) < eps) ? eps : dy;
  dsz = (fabsf(dz) < eps) ? eps : dz;
  invx = __builtin_amdgcn_rcpf(dsx);
  invy = __builtin_amdgcn_rcpf(dsy);
  invz = __builtin_amdgcn_rcpf(dsz);
  float a0 = (-1.0f - p0x) * invx, a1 = (1.0f - p0x) * invx;
  float axmin = fminf(a0, a1), axmax = fmaxf(a0, a1);
  a0 = (-1.0f - p0y) * invy; a1 = (1.0f - p0y) * invy;
  float aymin = fminf(a0, a1), aymax = fmaxf(a0, a1);
  a0 = (-1.0f - p0z) * invz; a1 = (1.0f - p0z) * invz;
  float azmin = fminf(a0, a1), azmax = fmaxf(a0, a1);
  amin = fmaxf(fmaxf(axmin, aymin), fmaxf(azmin, 0.0f));
  amax = fminf(fminf(axmax, aymax), fminf(azmax, 1.0f));
}

// --- image fp32 linear -> fp16 bricked ---------------------------------------
__global__ __launch_bounds__(256) void convert_brick(
    const float* __restrict__ img, __half* __restrict__ h)
{
  int i = blockIdx.x * blockDim.x + threadIdx.x;
  int stride = gridDim.x * blockDim.x;
  for (int hi = i; hi < NVOX; hi += stride) {
    int lz = hi & 3, ly = (hi >> 2) & 3, lx = (hi >> 4) & 3;
    int bz = (hi >> 6) & 31, by = (hi >> 11) & 31, bx = (hi >> 16) & 31;
    int ix = (bx << 2) | lx, iy = (by << 2) | ly, iz = (bz << 2) | lz;
    h[hi] = __float2half(img[(((ix << 7) | iy) << 7) | iz]);
  }
}

// --- traversal ---------------------------------------------------------------
__global__ __launch_bounds__(256) void siddon_fp(
    const __half* __restrict__ image,
    const float* __restrict__ lors,
    float* __restrict__ out, int n)
{
  int t   = blockIdx.x * blockDim.x + threadIdx.x;
  int ray = t >> LOGK;
  int k   = t & (K - 1);
  if (ray >= n) return;

  float p0x,p0y,p0z,dx,dy,dz,dsx,dsy,dsz,invx,invy,invz,amin,amax;
  ray_setup(lors + (long)ray * 6, p0x,p0y,p0z, dx,dy,dz,
            dsx,dsy,dsz, invx,invy,invz, amin,amax);

  float acc0 = 0.0f, acc1 = 0.0f;
  if (amax > amin) {
    float s      = (amax - amin) * (1.0f / (float)K);
    float astart = fmaf((float)k, s, amin);
    float aend   = (k == K - 1) ? amax : fmaf((float)(k + 1), s, amin);

    TState S;
    S.acur = astart; S.aend = aend;
    int c0, c1, c2;
    axis_init(astart, aend, p0x, dsx, invx, S.stx, S.ix, S.alx, S.dax, c0);
    axis_init(astart, aend, p0y, dsy, invy, S.sty, S.iy, S.aly, S.day, c1);
    axis_init(astart, aend, p0z, dsz, invz, S.stz, S.iz, S.alz, S.daz, c2);

    int ns = c0 + c1 + c2 + 2;          // segments = crossings+1, +1 margin
    int nb = (ns + 3) >> 2;             // batches of 4
    if (nb < 2) nb = 2;                 // prologue needs two batches

    float difA[4], difB[4], difC[4];
    float vA[4], vB[4], vC[4];

#define ISSUE(X)   step4(image, S, dif##X, v##X)
#define CONSUME(X)                                                  \
    do { acc0 = fmaf(dif##X[0], v##X[0], acc0);                     \
         acc1 = fmaf(dif##X[1], v##X[1], acc1);                     \
         acc0 = fmaf(dif##X[2], v##X[2], acc0);                     \
         acc1 = fmaf(dif##X[3], v##X[3], acc1); } while (0)

    ISSUE(A);
    ISSUE(B);
    int produce = nb - 2;
    while (produce >= 3) {
      ISSUE(C); CONSUME(A);
      ISSUE(A); CONSUME(B);
      ISSUE(B); CONSUME(C);
      produce -= 3;
    }
    if (produce == 2) {
      ISSUE(C); CONSUME(A);
      ISSUE(A); CONSUME(B);
      CONSUME(C); CONSUME(A);
    } else if (produce == 1) {
      ISSUE(C); CONSUME(A);
      CONSUME(B); CONSUME(C);
    } else {
      CONSUME(A); CONSUME(B);
    }
#undef ISSUE
#undef CONSUME

    float rlen = sqrtf(dx * dx + dy * dy + dz * dz);
    acc0 = (acc0 + acc1) * rlen;
    acc1 = 0.0f;
  }

  // reduce the K=16 chunk partials within each 16-lane group
  float acc = acc0 + acc1;
  acc += __shfl_xor(acc, 1);
  acc += __shfl_xor(acc, 2);
  acc += __shfl_xor(acc, 4);
  acc += __shfl_xor(acc, 8);
  if (k == 0) out[ray] = acc;
}

extern "C" void kernel_launch(void* const* d_in, const int* in_sizes, int n_in,
                              void* d_out, int out_size, void* d_ws, size_t ws_size,
                              hipStream_t stream) {
  const float* image = (const float*)d_in[0];   // [128,128,128] f32
  const float* lors  = (const float*)d_in[1];   // [N,6] f32
  float* out = (float*)d_out;                   // [N] f32
  int n = out_size;

  __half* h = (__half*)d_ws;                    // 4 MB bricked fp16 image
  hipLaunchKernelGGL(convert_brick, dim3(2048), dim3(256), 0, stream, image, h);

  long total = (long)n * K;
  int block = 256;
  int grid = (int)((total + block - 1) / block);
  hipLaunchKernelGGL(siddon_fp, dim3(grid), dim3(block), 0, stream,
                     h, lors, out, n);
}